// Round 1
// baseline (294.937 us; speedup 1.0000x reference)
//
#include <hip/hip_runtime.h>

#define BATCH 256
#define ICAPS 1152
#define OCAPS 10
#define CDIM  16
#define OD    160      // OCAPS*CDIM
#define CHUNK 256
#define NCHUNK 5       // ceil(1152/256); last chunk = 128

// Phase A: thread t = input capsule i; compute dots with v (LDS), update b_state,
//          softmax over o, write c to LDS.
// Phase B: thread t (<160) owns (o,d) pair; coalesced 640B-wide reads over the
//          chunk's i's, FMA with c from LDS, atomicAdd into s.
__global__ __launch_bounds__(256) void k_iter(const float* __restrict__ x,
                                              const float* __restrict__ v,
                                              float* __restrict__ bst,
                                              float* __restrict__ s,
                                              int iter) {
    __shared__ float c_lds[CHUNK][OCAPS];
    __shared__ __align__(16) float v_lds[OD];

    const int b  = blockIdx.y;
    const int i0 = blockIdx.x * CHUNK;
    const int ni = min(CHUNK, ICAPS - i0);
    const int t  = threadIdx.x;

    if (iter == 0) {
        // c = softmax(zeros) = 0.1 uniform: s = 0.1 * sum_i x
        if (t < OD) {
            const float* xp = x + ((size_t)b * ICAPS + i0) * OD + t;
            float a0 = 0.f, a1 = 0.f;
            int i = 0;
            for (; i + 1 < ni; i += 2) {
                a0 += xp[(size_t)i * OD];
                a1 += xp[(size_t)(i + 1) * OD];
            }
            if (i < ni) a0 += xp[(size_t)i * OD];
            atomicAdd(&s[b * OD + t], 0.1f * (a0 + a1));
        }
        return;
    }

    if (t < OD) v_lds[t] = v[b * OD + t];
    __syncthreads();

    if (t < ni) {
        const int i = i0 + t;
        const float* xp = x + ((size_t)b * ICAPS + i) * OD;
        float dots[OCAPS];
        #pragma unroll
        for (int o = 0; o < OCAPS; ++o) {
            float4 a0 = *(const float4*)(xp + o * 16 + 0);
            float4 a1 = *(const float4*)(xp + o * 16 + 4);
            float4 a2 = *(const float4*)(xp + o * 16 + 8);
            float4 a3 = *(const float4*)(xp + o * 16 + 12);
            const float4 w0 = *(const float4*)(v_lds + o * 16 + 0);
            const float4 w1 = *(const float4*)(v_lds + o * 16 + 4);
            const float4 w2 = *(const float4*)(v_lds + o * 16 + 8);
            const float4 w3 = *(const float4*)(v_lds + o * 16 + 12);
            float d0 = a0.x * w0.x + a0.y * w0.y + a0.z * w0.z + a0.w * w0.w;
            float d1 = a1.x * w1.x + a1.y * w1.y + a1.z * w1.z + a1.w * w1.w;
            float d2 = a2.x * w2.x + a2.y * w2.y + a2.z * w2.z + a2.w * w2.w;
            float d3 = a3.x * w3.x + a3.y * w3.y + a3.z * w3.z + a3.w * w3.w;
            dots[o] = (d0 + d1) + (d2 + d3);
        }

        float* bp = bst + ((size_t)b * ICAPS + i) * OCAPS;
        float bv[OCAPS];
        if (iter == 1) {
            #pragma unroll
            for (int o = 0; o < OCAPS; ++o) bv[o] = dots[o];
        } else {
            #pragma unroll
            for (int o = 0; o < OCAPS; ++o) bv[o] = bp[o] + dots[o];
        }
        #pragma unroll
        for (int o = 0; o < OCAPS; ++o) bp[o] = bv[o];

        // softmax over o (10)
        float m = bv[0];
        #pragma unroll
        for (int o = 1; o < OCAPS; ++o) m = fmaxf(m, bv[o]);
        float e[OCAPS], sum = 0.f;
        #pragma unroll
        for (int o = 0; o < OCAPS; ++o) { e[o] = __expf(bv[o] - m); sum += e[o]; }
        const float inv = 1.f / sum;
        #pragma unroll
        for (int o = 0; o < OCAPS; ++o) c_lds[t][o] = e[o] * inv;
    }
    __syncthreads();

    if (t < OD) {
        const int o = t >> 4;
        const float* xp = x + ((size_t)b * ICAPS + i0) * OD + t;
        float a0 = 0.f, a1 = 0.f;
        int i = 0;
        for (; i + 1 < ni; i += 2) {
            a0 += c_lds[i][o]     * xp[(size_t)i * OD];
            a1 += c_lds[i + 1][o] * xp[(size_t)(i + 1) * OD];
        }
        if (i < ni) a0 += c_lds[i][o] * xp[(size_t)i * OD];
        atomicAdd(&s[b * OD + t], a0 + a1);
    }
}

// v = s * sqrt(|s|^2) / (1 + |s|^2) over d (16-lane groups); zero s for next pass.
__global__ __launch_bounds__(256) void k_squash(float* __restrict__ s,
                                                float* __restrict__ vout) {
    const int t = blockIdx.x * blockDim.x + threadIdx.x; // 0..40959
    float sv = s[t];
    float sq = sv * sv;
    #pragma unroll
    for (int m = 1; m < 16; m <<= 1) sq += __shfl_xor(sq, m, 64);
    const float scale = sqrtf(sq) / (1.f + sq);
    vout[t] = sv * scale;
    s[t] = 0.f;
}

extern "C" void kernel_launch(void* const* d_in, const int* in_sizes, int n_in,
                              void* d_out, int out_size, void* d_ws, size_t ws_size,
                              hipStream_t stream) {
    const float* x = (const float*)d_in[0];
    float* vbuf = (float*)d_out;                       // 40960 floats, v lives here
    float* bst  = (float*)d_ws;                        // 256*1152*10 floats
    float* s    = bst + (size_t)BATCH * ICAPS * OCAPS; // 40960 floats

    hipMemsetAsync(s, 0, (size_t)BATCH * OD * sizeof(float), stream);

    dim3 grid(NCHUNK, BATCH), blk(256);
    for (int it = 0; it <= 3; ++it) {
        k_iter<<<grid, blk, 0, stream>>>(x, vbuf, bst, s, it);
        k_squash<<<160, 256, 0, stream>>>(s, vbuf);
    }
}

// Round 2
// 174.441 us; speedup vs baseline: 1.6908x; 1.6908x over previous
//
#include <hip/hip_runtime.h>

#define BATCH  256
#define ICAPS  1152
#define OCAPS  10
#define OD     160     // OCAPS*16
#define CHUNK  64      // input capsules per block
#define NCHUNK 18      // 1152/64, exact
#define PAD    164     // padded floats per LDS row (16B-aligned, bank-friendly)

// One kernel per routing step. Reads the x tile from global ONCE into LDS;
// dot-phase and weighted-sum phase both consume the LDS tile.
// b-state is never materialized: b_i = sum_tau dot(x_i, v_tau), with v_tau
// recomputed in-block from the tiny s_tau buffers (squash of 160 floats).
__global__ __launch_bounds__(256) void k_iter(const float* __restrict__ x,
                                              float* __restrict__ sbufs, // 4*BATCH*OD
                                              int iter) {
    __shared__ __align__(16) float xt[CHUNK * PAD];
    __shared__ float c_lds[CHUNK][OCAPS];
    __shared__ __align__(16) float v_lds[3 * OD];

    const int b  = blockIdx.y;
    const int i0 = blockIdx.x * CHUNK;
    const int t  = threadIdx.x;

    // ---- 1. stage x tile: 64 rows x 160 floats, contiguous in global ----
    const float4* src = (const float4*)(x + ((size_t)b * ICAPS + i0) * OD);
    #pragma unroll
    for (int k = 0; k < 10; ++k) {          // 2560 float4s / 256 threads
        const int f4  = t + k * 256;
        const int row = f4 / 40;            // 40 float4 per row
        const int c4  = f4 - row * 40;
        *(float4*)&xt[row * PAD + c4 * 4] = src[f4];
    }

    if (iter == 0) {
        if (t < CHUNK) {
            #pragma unroll
            for (int o = 0; o < OCAPS; ++o) c_lds[t][o] = 0.1f;
        }
    } else if (t < OD) {
        // ---- 2. recompute v_tau = squash(s_tau[b]) for tau < iter ----
        for (int tau = 0; tau < iter; ++tau) {
            const float sv = sbufs[tau * (BATCH * OD) + b * OD + t];
            float sq = sv * sv;
            #pragma unroll
            for (int m = 1; m < 16; m <<= 1) sq += __shfl_xor(sq, m, 64);
            v_lds[tau * OD + t] = sv * sqrtf(sq) / (1.f + sq);
        }
    }
    __syncthreads();

    // ---- 3. dot phase: thread t = row t; b_i = sum_tau <x_i, v_tau> ----
    if (iter > 0 && t < CHUNK) {
        float bv[OCAPS];
        #pragma unroll
        for (int o = 0; o < OCAPS; ++o) {
            const float4 a0 = *(const float4*)&xt[t * PAD + o * 16 + 0];
            const float4 a1 = *(const float4*)&xt[t * PAD + o * 16 + 4];
            const float4 a2 = *(const float4*)&xt[t * PAD + o * 16 + 8];
            const float4 a3 = *(const float4*)&xt[t * PAD + o * 16 + 12];
            float acc = 0.f;
            for (int tau = 0; tau < iter; ++tau) {
                const float4 w0 = *(const float4*)&v_lds[tau * OD + o * 16 + 0];
                const float4 w1 = *(const float4*)&v_lds[tau * OD + o * 16 + 4];
                const float4 w2 = *(const float4*)&v_lds[tau * OD + o * 16 + 8];
                const float4 w3 = *(const float4*)&v_lds[tau * OD + o * 16 + 12];
                const float d0 = a0.x*w0.x + a0.y*w0.y + a0.z*w0.z + a0.w*w0.w;
                const float d1 = a1.x*w1.x + a1.y*w1.y + a1.z*w1.z + a1.w*w1.w;
                const float d2 = a2.x*w2.x + a2.y*w2.y + a2.z*w2.z + a2.w*w2.w;
                const float d3 = a3.x*w3.x + a3.y*w3.y + a3.z*w3.z + a3.w*w3.w;
                acc += (d0 + d1) + (d2 + d3);
            }
            bv[o] = acc;
        }
        // softmax over o
        float m = bv[0];
        #pragma unroll
        for (int o = 1; o < OCAPS; ++o) m = fmaxf(m, bv[o]);
        float e[OCAPS], sum = 0.f;
        #pragma unroll
        for (int o = 0; o < OCAPS; ++o) { e[o] = __expf(bv[o] - m); sum += e[o]; }
        const float inv = 1.f / sum;
        #pragma unroll
        for (int o = 0; o < OCAPS; ++o) c_lds[t][o] = e[o] * inv;
    }
    __syncthreads();

    // ---- 4. weighted sum: thread t = (o,d) pair, accumulate over rows ----
    if (t < OD) {
        const int o = t >> 4;
        float a0 = 0.f, a1 = 0.f, a2 = 0.f, a3 = 0.f;
        #pragma unroll 4
        for (int i = 0; i < CHUNK; i += 4) {
            a0 += c_lds[i    ][o] * xt[(i    ) * PAD + t];
            a1 += c_lds[i + 1][o] * xt[(i + 1) * PAD + t];
            a2 += c_lds[i + 2][o] * xt[(i + 2) * PAD + t];
            a3 += c_lds[i + 3][o] * xt[(i + 3) * PAD + t];
        }
        atomicAdd(&sbufs[iter * (BATCH * OD) + b * OD + t], (a0 + a1) + (a2 + a3));
    }
}

// Final: v3 = squash(s3) -> d_out
__global__ __launch_bounds__(256) void k_squash(const float* __restrict__ s,
                                                float* __restrict__ vout) {
    const int t = blockIdx.x * blockDim.x + threadIdx.x; // 0..40959
    const float sv = s[t];
    float sq = sv * sv;
    #pragma unroll
    for (int m = 1; m < 16; m <<= 1) sq += __shfl_xor(sq, m, 64);
    vout[t] = sv * sqrtf(sq) / (1.f + sq);
}

extern "C" void kernel_launch(void* const* d_in, const int* in_sizes, int n_in,
                              void* d_out, int out_size, void* d_ws, size_t ws_size,
                              hipStream_t stream) {
    const float* x = (const float*)d_in[0];
    float* sbufs = (float*)d_ws;                  // 4 * 256*160 floats = 655 KB
    float* vout  = (float*)d_out;

    hipMemsetAsync(sbufs, 0, (size_t)4 * BATCH * OD * sizeof(float), stream);

    dim3 grid(NCHUNK, BATCH), blk(256);
    for (int it = 0; it <= 3; ++it)
        k_iter<<<grid, blk, 0, stream>>>(x, sbufs, it);
    k_squash<<<160, 256, 0, stream>>>(sbufs + 3 * BATCH * OD, vout);
}

// Round 3
// 173.217 us; speedup vs baseline: 1.7027x; 1.0071x over previous
//
#include <hip/hip_runtime.h>
#include <hip/hip_fp16.h>

#define BATCH  256
#define ICAPS  1152
#define OCAPS  10
#define OD     160     // OCAPS*16
#define CHUNK  64      // input capsules per block
#define NCHUNK 18      // 1152/64, exact
#define PAD    164     // padded floats per LDS row

// Pass 0: read fp32 x, stage tile in LDS, (a) write fp16 copy of x to ws,
// (b) s0 = 0.1 * sum_i x  (c is uniform 0.1 at iter 0).
__global__ __launch_bounds__(256) void k_conv0(const float* __restrict__ x,
                                               __half* __restrict__ x16,
                                               float* __restrict__ sbufs) {
    __shared__ __align__(16) float xt[CHUNK * PAD];
    const int b  = blockIdx.y;
    const int i0 = blockIdx.x * CHUNK;
    const int t  = threadIdx.x;
    const size_t gbase = ((size_t)b * ICAPS + i0) * OD;
    const float4* src  = (const float4*)(x + gbase);
    uint2* dst16       = (uint2*)(x16 + gbase);

    #pragma unroll
    for (int k = 0; k < 10; ++k) {          // 2560 float4 / 256 threads
        const int f4  = t + k * 256;
        const int row = f4 / 40;            // 40 float4 per row
        const int c4  = f4 - row * 40;
        const float4 v = src[f4];
        *(float4*)&xt[row * PAD + c4 * 4] = v;
        const __half2 h0 = __floats2half2_rn(v.x, v.y);
        const __half2 h1 = __floats2half2_rn(v.z, v.w);
        uint2 u;
        u.x = *(const unsigned*)&h0;
        u.y = *(const unsigned*)&h1;
        dst16[f4] = u;                      // coalesced 8B/lane
    }
    __syncthreads();

    if (t < OD) {
        float a0 = 0.f, a1 = 0.f, a2 = 0.f, a3 = 0.f;
        #pragma unroll 4
        for (int i = 0; i < CHUNK; i += 4) {
            a0 += xt[(i    ) * PAD + t];
            a1 += xt[(i + 1) * PAD + t];
            a2 += xt[(i + 2) * PAD + t];
            a3 += xt[(i + 3) * PAD + t];
        }
        atomicAdd(&sbufs[b * OD + t], 0.1f * ((a0 + a1) + (a2 + a3)));
    }
}

// Iters 1..3: read fp16 x, stage as fp32 in LDS; dot vs v_{iter-1} (recomputed
// in-block from s buffers), softmax -> c, weighted sum -> s_iter.
__global__ __launch_bounds__(256) void k_iter(const __half* __restrict__ x16,
                                              float* __restrict__ sbufs,
                                              int iter) {
    __shared__ __align__(16) float xt[CHUNK * PAD];
    __shared__ float c_lds[CHUNK][OCAPS];
    __shared__ __align__(16) float v_lds[3 * OD];

    const int b  = blockIdx.y;
    const int i0 = blockIdx.x * CHUNK;
    const int t  = threadIdx.x;
    const size_t gbase = ((size_t)b * ICAPS + i0) * OD;
    const uint4* src = (const uint4*)(x16 + gbase);   // 8 halves per uint4

    #pragma unroll
    for (int k = 0; k < 5; ++k) {           // 1280 uint4 / 256 threads
        const int j   = t + k * 256;
        const int row = j / 20;             // 20 uint4 per row
        const int c8  = j - row * 20;
        const uint4 p = src[j];
        float* d = &xt[row * PAD + c8 * 8];
        const float2 f0 = __half22float2(*(const __half2*)&p.x);
        const float2 f1 = __half22float2(*(const __half2*)&p.y);
        const float2 f2 = __half22float2(*(const __half2*)&p.z);
        const float2 f3 = __half22float2(*(const __half2*)&p.w);
        d[0] = f0.x; d[1] = f0.y; d[2] = f1.x; d[3] = f1.y;
        d[4] = f2.x; d[5] = f2.y; d[6] = f3.x; d[7] = f3.y;
    }

    if (t < OD) {
        // recompute v_tau = squash(s_tau[b]) for tau < iter (160 lanes, shfl over d)
        for (int tau = 0; tau < iter; ++tau) {
            const float sv = sbufs[tau * (BATCH * OD) + b * OD + t];
            float sq = sv * sv;
            #pragma unroll
            for (int m = 1; m < 16; m <<= 1) sq += __shfl_xor(sq, m, 64);
            v_lds[tau * OD + t] = sv * sqrtf(sq) / (1.f + sq);
        }
    }
    __syncthreads();

    // dot phase: thread t = row; b_i = sum_tau <x_i, v_tau>; softmax -> c
    if (t < CHUNK) {
        float bv[OCAPS];
        #pragma unroll
        for (int o = 0; o < OCAPS; ++o) {
            const float4 a0 = *(const float4*)&xt[t * PAD + o * 16 + 0];
            const float4 a1 = *(const float4*)&xt[t * PAD + o * 16 + 4];
            const float4 a2 = *(const float4*)&xt[t * PAD + o * 16 + 8];
            const float4 a3 = *(const float4*)&xt[t * PAD + o * 16 + 12];
            float acc = 0.f;
            for (int tau = 0; tau < iter; ++tau) {
                const float4 w0 = *(const float4*)&v_lds[tau * OD + o * 16 + 0];
                const float4 w1 = *(const float4*)&v_lds[tau * OD + o * 16 + 4];
                const float4 w2 = *(const float4*)&v_lds[tau * OD + o * 16 + 8];
                const float4 w3 = *(const float4*)&v_lds[tau * OD + o * 16 + 12];
                const float d0 = a0.x*w0.x + a0.y*w0.y + a0.z*w0.z + a0.w*w0.w;
                const float d1 = a1.x*w1.x + a1.y*w1.y + a1.z*w1.z + a1.w*w1.w;
                const float d2 = a2.x*w2.x + a2.y*w2.y + a2.z*w2.z + a2.w*w2.w;
                const float d3 = a3.x*w3.x + a3.y*w3.y + a3.z*w3.z + a3.w*w3.w;
                acc += (d0 + d1) + (d2 + d3);
            }
            bv[o] = acc;
        }
        float m = bv[0];
        #pragma unroll
        for (int o = 1; o < OCAPS; ++o) m = fmaxf(m, bv[o]);
        float e[OCAPS], sum = 0.f;
        #pragma unroll
        for (int o = 0; o < OCAPS; ++o) { e[o] = __expf(bv[o] - m); sum += e[o]; }
        const float inv = 1.f / sum;
        #pragma unroll
        for (int o = 0; o < OCAPS; ++o) c_lds[t][o] = e[o] * inv;
    }
    __syncthreads();

    // weighted sum: thread t = (o,d) pair
    if (t < OD) {
        const int o = t >> 4;
        float a0 = 0.f, a1 = 0.f, a2 = 0.f, a3 = 0.f;
        #pragma unroll 4
        for (int i = 0; i < CHUNK; i += 4) {
            a0 += c_lds[i    ][o] * xt[(i    ) * PAD + t];
            a1 += c_lds[i + 1][o] * xt[(i + 1) * PAD + t];
            a2 += c_lds[i + 2][o] * xt[(i + 2) * PAD + t];
            a3 += c_lds[i + 3][o] * xt[(i + 3) * PAD + t];
        }
        atomicAdd(&sbufs[iter * (BATCH * OD) + b * OD + t], (a0 + a1) + (a2 + a3));
    }
}

// Final: v3 = squash(s3) -> d_out
__global__ __launch_bounds__(256) void k_squash(const float* __restrict__ s,
                                                float* __restrict__ vout) {
    const int t = blockIdx.x * blockDim.x + threadIdx.x; // 0..40959
    const float sv = s[t];
    float sq = sv * sv;
    #pragma unroll
    for (int m = 1; m < 16; m <<= 1) sq += __shfl_xor(sq, m, 64);
    vout[t] = sv * sqrtf(sq) / (1.f + sq);
}

extern "C" void kernel_launch(void* const* d_in, const int* in_sizes, int n_in,
                              void* d_out, int out_size, void* d_ws, size_t ws_size,
                              hipStream_t stream) {
    const float* x = (const float*)d_in[0];
    float* sbufs = (float*)d_ws;                               // 4*256*160 f32
    __half* x16  = (__half*)((char*)d_ws + (size_t)4 * BATCH * OD * sizeof(float));
    float* vout  = (float*)d_out;

    hipMemsetAsync(sbufs, 0, (size_t)4 * BATCH * OD * sizeof(float), stream);

    dim3 grid(NCHUNK, BATCH), blk(256);
    k_conv0<<<grid, blk, 0, stream>>>(x, x16, sbufs);
    for (int it = 1; it <= 3; ++it)
        k_iter<<<grid, blk, 0, stream>>>(x16, sbufs, it);
    k_squash<<<160, 256, 0, stream>>>(sbufs + 3 * BATCH * OD, vout);
}

// Round 5
// 121.150 us; speedup vs baseline: 2.4345x; 1.4298x over previous
//
#include <hip/hip_runtime.h>
#include <hip/hip_fp16.h>

#define BATCH  256
#define ICAPS  1152
#define OCAPS  10
#define OD     160            // OCAPS*16
#define BLOCK  960            // 15 waves
#define NPASS  12             // 11520 dot units / 960 threads
#define RGB    48             // row groups (phase B / iter0)
#define RPGB   24             // rows per group (1152/48)

// One persistent block per batch element b. All 4 routing steps run inside
// the block. b-state (routing logits) is held in registers: thread t owns
// dot-units u = p*BLOCK + t for p<NPASS, identical every iteration, so
// breg[p] accumulates sum_tau <x_u, v_tau> as the reference requires.
__global__ __launch_bounds__(BLOCK, 1) void k_routing(const float* __restrict__ x,
                                                      __half* __restrict__ x16,
                                                      float* __restrict__ out) {
    __shared__ float bc[ICAPS * OCAPS + 1152];   // per-iter logits, then c (in place)
    __shared__ float part[RGB][OD];              // 30.7 KB partial col-sums
    __shared__ __align__(16) float v_lds[OD];

    const int b = blockIdx.x;
    const int t = threadIdx.x;
    const size_t xb = (size_t)b * (ICAPS * OD);

    const int c8  = t % 20;        // 8-col block 0..19
    const int rgb = t / 20;        // row group 0..47
    const int oB  = c8 >> 1;       // output capsule for phase B

    const float* xp  = x + xb;
    __half*      hpw = x16 + xb;
    const __half* hp = x16 + xb;

    float breg[NPASS];             // accumulated routing logits (b-state)
    #pragma unroll
    for (int p = 0; p < NPASS; ++p) breg[p] = 0.f;

    // ---------------- iter 0: col-sums (c = 0.1) + fp32 -> fp16 conversion ----------------
    {
        float a[8] = {0,0,0,0,0,0,0,0};
        #pragma unroll 4
        for (int k = 0; k < RPGB; ++k) {
            const int r = rgb * RPGB + k;
            const float4 v0 = *(const float4*)(xp + r * OD + c8 * 8);
            const float4 v1 = *(const float4*)(xp + r * OD + c8 * 8 + 4);
            __half2 h0 = __floats2half2_rn(v0.x, v0.y);
            __half2 h1 = __floats2half2_rn(v0.z, v0.w);
            __half2 h2 = __floats2half2_rn(v1.x, v1.y);
            __half2 h3 = __floats2half2_rn(v1.z, v1.w);
            uint4 u;
            u.x = *(unsigned*)&h0; u.y = *(unsigned*)&h1;
            u.z = *(unsigned*)&h2; u.w = *(unsigned*)&h3;
            *(uint4*)(hpw + r * OD + c8 * 8) = u;     // coalesced 16B/lane
            a[0]+=v0.x; a[1]+=v0.y; a[2]+=v0.z; a[3]+=v0.w;
            a[4]+=v1.x; a[5]+=v1.y; a[6]+=v1.z; a[7]+=v1.w;
        }
        float* pp = &part[rgb][c8 * 8];
        #pragma unroll
        for (int j = 0; j < 8; ++j) pp[j] = a[j];
    }
    __syncthreads();
    if (t < OD) {     // reduce + 0.1 scale + squash -> v0
        float s = 0.f;
        #pragma unroll
        for (int g = 0; g < RGB; ++g) s += part[g][t];
        s *= 0.1f;
        float sq = s * s;
        #pragma unroll
        for (int m = 1; m < 16; m <<= 1) sq += __shfl_xor(sq, m, 64);
        v_lds[t] = s * sqrtf(sq) / (1.f + sq);
    }
    __syncthreads();

    // ---------------- iters 1..3 ----------------
    for (int it = 1; it <= 3; ++it) {
        // phase A: dot units (row,o); lanes consecutive -> 2KB contiguous reads/wave
        #pragma unroll 3
        for (int p = 0; p < NPASS; ++p) {
            const int u   = p * BLOCK + t;
            const int row = u / 10;
            const int o   = u - row * 10;
            const uint4 q0 = *(const uint4*)(hp + row * OD + o * 16);
            const uint4 q1 = *(const uint4*)(hp + row * OD + o * 16 + 8);
            const float4 w0 = *(const float4*)&v_lds[o * 16 + 0];
            const float4 w1 = *(const float4*)&v_lds[o * 16 + 4];
            const float4 w2 = *(const float4*)&v_lds[o * 16 + 8];
            const float4 w3 = *(const float4*)&v_lds[o * 16 + 12];
            float2 f0 = __half22float2(*(const __half2*)&q0.x);
            float2 f1 = __half22float2(*(const __half2*)&q0.y);
            float2 f2 = __half22float2(*(const __half2*)&q0.z);
            float2 f3 = __half22float2(*(const __half2*)&q0.w);
            const float d0 = f0.x*w0.x + f0.y*w0.y + f1.x*w0.z + f1.y*w0.w;
            const float d1 = f2.x*w1.x + f2.y*w1.y + f3.x*w1.z + f3.y*w1.w;
            f0 = __half22float2(*(const __half2*)&q1.x);
            f1 = __half22float2(*(const __half2*)&q1.y);
            f2 = __half22float2(*(const __half2*)&q1.z);
            f3 = __half22float2(*(const __half2*)&q1.w);
            const float d2 = f0.x*w2.x + f0.y*w2.y + f1.x*w2.z + f1.y*w2.w;
            const float d3 = f2.x*w3.x + f2.y*w3.y + f3.x*w3.z + f3.y*w3.w;
            breg[p] += (d0 + d1) + (d2 + d3);   // b accumulates across iterations
            bc[u] = breg[p];
        }
        __syncthreads();

        // per-row softmax over o, in place in bc
        for (int r = t; r < ICAPS; r += BLOCK) {
            float bv[OCAPS];
            #pragma unroll
            for (int o = 0; o < OCAPS; ++o) bv[o] = bc[r * 10 + o];
            float m = bv[0];
            #pragma unroll
            for (int o = 1; o < OCAPS; ++o) m = fmaxf(m, bv[o]);
            float e[OCAPS], sum = 0.f;
            #pragma unroll
            for (int o = 0; o < OCAPS; ++o) { e[o] = __expf(bv[o] - m); sum += e[o]; }
            const float inv = 1.f / sum;
            #pragma unroll
            for (int o = 0; o < OCAPS; ++o) bc[r * 10 + o] = e[o] * inv;
        }
        __syncthreads();

        // phase B: weighted col-sums; lanes consecutive -> coalesced 16B/lane
        {
            float a[8] = {0,0,0,0,0,0,0,0};
            #pragma unroll 4
            for (int k = 0; k < RPGB; ++k) {
                const int r = rgb * RPGB + k;
                const uint4 h = *(const uint4*)(hp + r * OD + c8 * 8);
                const float cc = bc[r * 10 + oB];
                const float2 g0 = __half22float2(*(const __half2*)&h.x);
                const float2 g1 = __half22float2(*(const __half2*)&h.y);
                const float2 g2 = __half22float2(*(const __half2*)&h.z);
                const float2 g3 = __half22float2(*(const __half2*)&h.w);
                a[0] += cc*g0.x; a[1] += cc*g0.y; a[2] += cc*g1.x; a[3] += cc*g1.y;
                a[4] += cc*g2.x; a[5] += cc*g2.y; a[6] += cc*g3.x; a[7] += cc*g3.y;
            }
            float* pp = &part[rgb][c8 * 8];
            #pragma unroll
            for (int j = 0; j < 8; ++j) pp[j] = a[j];
        }
        __syncthreads();

        if (t < OD) {   // reduce + squash
            float s = 0.f;
            #pragma unroll
            for (int g = 0; g < RGB; ++g) s += part[g][t];
            float sq = s * s;
            #pragma unroll
            for (int m = 1; m < 16; m <<= 1) sq += __shfl_xor(sq, m, 64);
            const float scale = sqrtf(sq) / (1.f + sq);
            if (it == 3) out[(size_t)b * OD + t] = s * scale;
            else         v_lds[t] = s * scale;
        }
        __syncthreads();
    }
}

extern "C" void kernel_launch(void* const* d_in, const int* in_sizes, int n_in,
                              void* d_out, int out_size, void* d_ws, size_t ws_size,
                              hipStream_t stream) {
    const float* x = (const float*)d_in[0];
    __half* x16 = (__half*)d_ws;             // 256*1152*160 halves = 94.4 MB
    float* vout = (float*)d_out;
    k_routing<<<BATCH, BLOCK, 0, stream>>>(x, x16, vout);
}